// Round 1
// baseline (236.611 us; speedup 1.0000x reference)
//
#include <hip/hip_runtime.h>
#include <hip/hip_fp16.h>
#include <hip/hip_bf16.h>
#include <math.h>

// GAT 2-layer forward, MI355X. FP32 in/out, int32 edge_index.
// R14: single-pass fused aggregation kernels. k_agg1/k_agg2 rewritten:
// no LDS edge cache, no two-phase (softmax linearity: accumulate e and e*h,
// divide at end), 16 nodes/wave (4 lanes/node) for 4x memory-level
// parallelism. Per-lane running sum IS the full denominator (every lane
// walks every edge of its node) -> zero cross-lane reduces in agg1.
// scatter/build/gemm1/gemm2 unchanged from R13.

#define LRELU(v) ((v) > 0.f ? (v) : 0.2f * (v))
#define BSH 8            // 256 nodes per bucket
#define BCAP 5120        // staged capacity per bucket
#define CHK 8192         // edges per k_scatter block

typedef __attribute__((ext_vector_type(8))) short short8;
typedef __attribute__((ext_vector_type(8))) _Float16 half8;
typedef __attribute__((ext_vector_type(4))) _Float16 half4;
typedef __attribute__((ext_vector_type(4))) float float4v;

static __device__ __forceinline__ short f2bf(float f) {
    __hip_bfloat16 b = __float2bfloat16(f);
    return *reinterpret_cast<short*>(&b);
}

// Pass 1 (scan-free): histogram -> reserve per-bucket global runs -> direct
// writes into contiguous runs. No LDS reorder, no prefix scans.
__global__ __launch_bounds__(256) void k_scatter(const int* __restrict__ ei, int* __restrict__ cursor,
                                                 int* __restrict__ stage, int E, int NBK) {
    __shared__ int hist[512];
    __shared__ int cnt2[512];
    __shared__ int base[512];
    int tid = threadIdx.x;
    int e0 = blockIdx.x * CHK;
    int nedge = E - e0; if (nedge > CHK) nedge = CHK;

    for (int i = tid; i < 512; i += 256) { hist[i] = 0; cnt2[i] = 0; }
    __syncthreads();
    for (int j = tid; j < nedge; j += 256) {
        int d = ei[E + e0 + j];
        atomicAdd(&hist[d >> BSH], 1);
    }
    __syncthreads();
    for (int b = tid; b < NBK; b += 256) {
        int c = hist[b];
        if (c > 0) base[b] = b * BCAP + atomicAdd(&cursor[b], c);
    }
    __syncthreads();
    for (int j = tid; j < nedge; j += 256) {
        int s = ei[e0 + j];
        int d = ei[E + e0 + j];
        int b = d >> BSH;
        int r = atomicAdd(&cnt2[b], 1);
        stage[base[b] + r] = s | ((d & ((1 << BSH) - 1)) << 17);
    }
}

// Pass 2: per-bucket fine CSR build. Block 0 also writes row_start[N],
// Wc (gemm1 att columns) and Wc2/Wd2 (gemm2 att columns).
__global__ __launch_bounds__(256) void k_build(const int* __restrict__ stage,
                                               const int* __restrict__ cursor,
                                               int* __restrict__ row_start,
                                               int* __restrict__ csr,
                                               const float* __restrict__ W1,
                                               const float* __restrict__ att_src,
                                               const float* __restrict__ att_dst,
                                               float* __restrict__ Wc,
                                               const float* __restrict__ W2,
                                               const float* __restrict__ att_src2,
                                               const float* __restrict__ att_dst2,
                                               float* __restrict__ Wc2,
                                               int NBK, int E, int N) {
    __shared__ int cnt[256];
    __shared__ int lb[256];
    __shared__ int cur[256];
    __shared__ int sA[256];
    int b = blockIdx.x, tid = threadIdx.x;
    int nodes0 = b << BSH;
    int nnodes = N - nodes0; if (nnodes > 256) nnodes = 256;
    int partial = 0;
    for (int i = tid; i < b; i += 256) partial += cursor[i];
    sA[tid] = partial;
    __syncthreads();
    for (int off = 128; off >= 1; off >>= 1) {
        if (tid < off) sA[tid] += sA[tid + off];
        __syncthreads();
    }
    int ebase = sA[0];
    int ecnt = cursor[b];
    __syncthreads();
    if (b == 0) {
        if (tid == 0) row_start[N] = E + N;
        for (int i = tid; i < 16 * 128; i += 256) {
            int col = i >> 7, k = i & 127;
            float v = 0.f;
            if (col < 8) {
                int h = col & 3;
                const float* att = (col < 4) ? att_src : att_dst;
                #pragma unroll
                for (int c = 0; c < 16; c++) v += W1[k * 64 + h * 16 + c] * att[h * 16 + c];
            }
            Wc[i] = v;
        }
        // Wc2: col0 = W2@att_src2 (64), col1 = W2@att_dst2 (64)
        for (int i = tid; i < 128; i += 256) {
            int col = i >> 6, k = i & 63;
            const float* att = col ? att_dst2 : att_src2;
            float v = 0.f;
            #pragma unroll
            for (int c = 0; c < 16; c++) v += W2[k * 16 + c] * att[c];
            Wc2[i] = v;
        }
    }
    const int* sbk = stage + b * BCAP;
    cnt[tid] = (tid < nnodes) ? 1 : 0;  // self loop
    __syncthreads();
    for (int e = tid; e < ecnt; e += 256) {
        int l = (sbk[e] >> 17) & 255;
        atomicAdd(&cnt[l], 1);
    }
    __syncthreads();
    int myc = cnt[tid];
    sA[tid] = myc;
    __syncthreads();
    for (int off = 1; off < 256; off <<= 1) {
        int r = sA[tid] + ((tid >= off) ? sA[tid - off] : 0);
        __syncthreads();
        sA[tid] = r;
        __syncthreads();
    }
    int gb = ebase + nodes0;
    lb[tid] = sA[tid] - myc;
    cur[tid] = 1;
    __syncthreads();
    if (tid < nnodes) {
        row_start[nodes0 + tid] = gb + lb[tid];
        csr[gb + lb[tid]] = nodes0 + tid;
    }
    __syncthreads();
    for (int e = tid; e < ecnt; e += 256) {
        int v = sbk[e];
        int l = (v >> 17) & 255;
        int src = v & 0x1FFFF;
        int r = atomicAdd(&cur[l], 1);
        csr[gb + lb[l] + r] = src;
    }
}

// h1[N,64](fp16) = x[N,128] @ W1[128,64] via MFMA 16x16x32 bf16 (R9).
__global__ __launch_bounds__(256) void k_gemm1(const float* __restrict__ x,
                                               const float* __restrict__ W1,
                                               const float* __restrict__ Wc,
                                               __half* __restrict__ h1, float* __restrict__ a_src,
                                               float* __restrict__ a_dst, int N) {
    __shared__ short wt[80 * 136];   // cols 0-63: W1^T; cols 64-79: Wc
    int tid = threadIdx.x;
    for (int i = tid; i < 128 * 64; i += 256) {
        int k = i >> 6, c = i & 63;
        wt[c * 136 + k] = f2bf(W1[i]);
    }
    for (int i = tid; i < 16 * 128; i += 256) {
        int col = i >> 7, k = i & 127;
        wt[(64 + col) * 136 + k] = f2bf(Wc[i]);
    }
    __syncthreads();
    int wave = tid >> 6, lane = tid & 63;
    int m = lane & 15, q = lane >> 4;
    int nbase = blockIdx.x * 64 + wave * 16;
    int anode = nbase + m;
    bool rowok = anode < N;
    const float* xrow = x + (size_t)(rowok ? anode : 0) * 128 + q * 8;

    float4v acc[5];
    #pragma unroll
    for (int ct = 0; ct < 5; ct++)
        #pragma unroll
        for (int r = 0; r < 4; r++) acc[ct][r] = 0.f;

    #pragma unroll
    for (int kc = 0; kc < 4; kc++) {
        float4 u0 = make_float4(0.f, 0.f, 0.f, 0.f), u1 = u0;
        if (rowok) {
            u0 = *(const float4*)(xrow + kc * 32);
            u1 = *(const float4*)(xrow + kc * 32 + 4);
        }
        short8 af;
        af[0] = f2bf(u0.x); af[1] = f2bf(u0.y); af[2] = f2bf(u0.z); af[3] = f2bf(u0.w);
        af[4] = f2bf(u1.x); af[5] = f2bf(u1.y); af[6] = f2bf(u1.z); af[7] = f2bf(u1.w);
        #pragma unroll
        for (int ct = 0; ct < 5; ct++) {
            short8 bf = *(const short8*)&wt[(ct * 16 + m) * 136 + kc * 32 + q * 8];
            acc[ct] = __builtin_amdgcn_mfma_f32_16x16x32_bf16(af, bf, acc[ct], 0, 0, 0);
        }
    }
    #pragma unroll
    for (int ct = 0; ct < 4; ct++) {
        #pragma unroll
        for (int r = 0; r < 4; r++) {
            int n = nbase + q * 4 + r;
            if (n < N) h1[(size_t)n * 64 + ct * 16 + m] = __float2half(acc[ct][r]);
        }
    }
    #pragma unroll
    for (int r = 0; r < 4; r++) {
        int n = nbase + q * 4 + r;
        if (n < N) {
            float v = acc[4][r];
            if (m < 4) a_src[n * 4 + m] = v;
            else if (m < 8) a_dst[n * 4 + (m - 4)] = v;
        }
    }
}

// layer-1 aggregation, single-pass fused (R14): 16 nodes/wave, 4 lanes/node.
// lane sub = head index; lane owns channels [sub*16, sub*16+16).
// Per edge: a_src gather (4B, 16B/group), e = exp(lrelu), h1 row gather
// (2x half8 per lane, 128B/group coalesced), A[c] += e*h1. Denominator is
// the per-lane running sum (each lane walks every edge) -> no reduce.
__global__ __launch_bounds__(256) void k_agg1(const int* __restrict__ row_start,
                                              const int* __restrict__ csr_src,
                                              const float* __restrict__ a_src,
                                              const float* __restrict__ a_dst,
                                              const __half* __restrict__ h1,
                                              const float* __restrict__ bias,
                                              __half* __restrict__ out1, int N) {
    int tid = threadIdx.x;
    int wave = tid >> 6, lane = tid & 63;
    int grp = lane >> 2, sub = lane & 3;
    int node = blockIdx.x * 64 + wave * 16 + grp;
    if (node >= N) return;
    int row = row_start[node];
    int deg = row_start[node + 1] - row;
    float adm = a_dst[node * 4 + sub];
    const _Float16* hb = (const _Float16*)h1 + sub * 16;
    float A[16];
    #pragma unroll
    for (int c = 0; c < 16; c++) A[c] = 0.f;
    float sh = 0.f;
    int j = 0;
    for (; j + 4 <= deg; j += 4) {
        int s0 = csr_src[row + j + 0];
        int s1 = csr_src[row + j + 1];
        int s2 = csr_src[row + j + 2];
        int s3 = csr_src[row + j + 3];
        float x0 = a_src[s0 * 4 + sub] + adm;
        float x1 = a_src[s1 * 4 + sub] + adm;
        float x2 = a_src[s2 * 4 + sub] + adm;
        float x3 = a_src[s3 * 4 + sub] + adm;
        half8 p0 = *(const half8*)(hb + (size_t)s0 * 64);
        half8 q0 = *(const half8*)(hb + (size_t)s0 * 64 + 8);
        half8 p1 = *(const half8*)(hb + (size_t)s1 * 64);
        half8 q1 = *(const half8*)(hb + (size_t)s1 * 64 + 8);
        half8 p2 = *(const half8*)(hb + (size_t)s2 * 64);
        half8 q2 = *(const half8*)(hb + (size_t)s2 * 64 + 8);
        half8 p3 = *(const half8*)(hb + (size_t)s3 * 64);
        half8 q3 = *(const half8*)(hb + (size_t)s3 * 64 + 8);
        float e0 = __expf(fmaxf(x0, 0.2f * x0));
        float e1 = __expf(fmaxf(x1, 0.2f * x1));
        float e2 = __expf(fmaxf(x2, 0.2f * x2));
        float e3 = __expf(fmaxf(x3, 0.2f * x3));
        sh += (e0 + e1) + (e2 + e3);
        #pragma unroll
        for (int c = 0; c < 8; c++) {
            A[c]     += e0 * (float)p0[c] + e1 * (float)p1[c]
                      + e2 * (float)p2[c] + e3 * (float)p3[c];
            A[c + 8] += e0 * (float)q0[c] + e1 * (float)q1[c]
                      + e2 * (float)q2[c] + e3 * (float)q3[c];
        }
    }
    for (; j < deg; j++) {
        int s = csr_src[row + j];
        float xv = a_src[s * 4 + sub] + adm;
        half8 p = *(const half8*)(hb + (size_t)s * 64);
        half8 q = *(const half8*)(hb + (size_t)s * 64 + 8);
        float e = __expf(fmaxf(xv, 0.2f * xv));
        sh += e;
        #pragma unroll
        for (int c = 0; c < 8; c++) {
            A[c]     += e * (float)p[c];
            A[c + 8] += e * (float)q[c];
        }
    }
    float iv = 1.f / (sh + 1e-16f);
    const float4* bb = (const float4*)bias + sub * 4;
    union { __half2 h2v[8]; float4 f4[2]; } pk;
    #pragma unroll
    for (int c4 = 0; c4 < 4; c4++) {
        float4 b = bb[c4];
        float o0 = A[c4 * 4 + 0] * iv + b.x;
        float o1 = A[c4 * 4 + 1] * iv + b.y;
        float o2 = A[c4 * 4 + 2] * iv + b.z;
        float o3 = A[c4 * 4 + 3] * iv + b.w;
        o0 = (o0 > 0.f) ? o0 : (__expf(o0) - 1.f);
        o1 = (o1 > 0.f) ? o1 : (__expf(o1) - 1.f);
        o2 = (o2 > 0.f) ? o2 : (__expf(o2) - 1.f);
        o3 = (o3 > 0.f) ? o3 : (__expf(o3) - 1.f);
        pk.h2v[c4 * 2 + 0] = __floats2half2_rn(o0, o1);
        pk.h2v[c4 * 2 + 1] = __floats2half2_rn(o2, o3);
    }
    *(float4*)&out1[(size_t)node * 64 + sub * 16]     = pk.f4[0];
    *(float4*)&out1[(size_t)node * 64 + sub * 16 + 8] = pk.f4[1];
}

// h2[N,16](fp16) = out1[N,64](fp16) @ W2[64,16] via MFMA f16; att2 dots
// via folded Wc2/Wd2 columns (2nd B-frag) — shuffle-free epilogue.
__global__ __launch_bounds__(256) void k_gemm2(const __half* __restrict__ out1,
                                               const float* __restrict__ W2,
                                               const float* __restrict__ Wc2,
                                               __half* __restrict__ h2, float* __restrict__ a_src,
                                               float* __restrict__ a_dst, int N) {
    __shared__ _Float16 wt2[16][72];   // wt2[c][k] = W2[k][c]
    __shared__ _Float16 wtb[16][72];   // col0 = Wc2, col1 = Wd2, rest 0
    int tid = threadIdx.x;
    for (int i = tid; i < 16 * 64; i += 256) {
        int k = i >> 4, c = i & 15;
        wt2[c][k] = (_Float16)W2[i];
    }
    for (int i = tid; i < 16 * 64; i += 256) {
        int col = i >> 6, k = i & 63;
        wtb[col][k] = (col < 2) ? (_Float16)Wc2[col * 64 + k] : (_Float16)0.f;
    }
    __syncthreads();
    int wave = tid >> 6, lane = tid & 63;
    int m = lane & 15, q = lane >> 4;
    int nbase = blockIdx.x * 64 + wave * 16;
    int anode = nbase + m;
    bool ok = anode < N;
    const __half* arow = out1 + (size_t)(ok ? anode : 0) * 64 + q * 8;

    float4v c1 = {0.f, 0.f, 0.f, 0.f}, c2v = {0.f, 0.f, 0.f, 0.f};
    #pragma unroll
    for (int kc = 0; kc < 2; kc++) {
        half8 af = *(const half8*)(arow + kc * 32);
        half8 b1 = *(const half8*)&wt2[m][kc * 32 + q * 8];
        half8 b2 = *(const half8*)&wtb[m][kc * 32 + q * 8];
        c1  = __builtin_amdgcn_mfma_f32_16x16x32_f16(af, b1, c1, 0, 0, 0);
        c2v = __builtin_amdgcn_mfma_f32_16x16x32_f16(af, b2, c2v, 0, 0, 0);
    }
    #pragma unroll
    for (int r = 0; r < 4; r++) {
        int n = nbase + q * 4 + r;
        if (n < N) {
            h2[(size_t)n * 16 + m] = __float2half(c1[r]);
            if (m == 0) a_src[n] = c2v[r];
            else if (m == 1) a_dst[n] = c2v[r];
        }
    }
}

// layer-2 aggregation + bias + log_softmax, single-pass fused (R14):
// 16 nodes/wave, 4 lanes/node; lane owns channels [sub*4, sub*4+4).
__global__ __launch_bounds__(256) void k_agg2(const int* __restrict__ row_start,
                                              const int* __restrict__ csr_src,
                                              const float* __restrict__ a_src,
                                              const float* __restrict__ a_dst,
                                              const __half* __restrict__ h2,
                                              const float* __restrict__ bias,
                                              float* __restrict__ out, int N) {
    int tid = threadIdx.x;
    int wave = tid >> 6, lane = tid & 63;
    int grp = lane >> 2, sub = lane & 3;
    int node = blockIdx.x * 64 + wave * 16 + grp;
    if (node >= N) return;
    int row = row_start[node];
    int deg = row_start[node + 1] - row;
    float ad = a_dst[node];
    const _Float16* hb = (const _Float16*)h2 + sub * 4;
    float A0 = 0.f, A1 = 0.f, A2 = 0.f, A3 = 0.f;
    float sh = 0.f;
    int j = 0;
    for (; j + 4 <= deg; j += 4) {
        int s0 = csr_src[row + j + 0];
        int s1 = csr_src[row + j + 1];
        int s2 = csr_src[row + j + 2];
        int s3 = csr_src[row + j + 3];
        float x0 = a_src[s0] + ad;
        float x1 = a_src[s1] + ad;
        float x2 = a_src[s2] + ad;
        float x3 = a_src[s3] + ad;
        half4 v0 = *(const half4*)(hb + (size_t)s0 * 16);
        half4 v1 = *(const half4*)(hb + (size_t)s1 * 16);
        half4 v2 = *(const half4*)(hb + (size_t)s2 * 16);
        half4 v3 = *(const half4*)(hb + (size_t)s3 * 16);
        float e0 = __expf(fmaxf(x0, 0.2f * x0));
        float e1 = __expf(fmaxf(x1, 0.2f * x1));
        float e2 = __expf(fmaxf(x2, 0.2f * x2));
        float e3 = __expf(fmaxf(x3, 0.2f * x3));
        sh += (e0 + e1) + (e2 + e3);
        A0 += e0 * (float)v0[0] + e1 * (float)v1[0] + e2 * (float)v2[0] + e3 * (float)v3[0];
        A1 += e0 * (float)v0[1] + e1 * (float)v1[1] + e2 * (float)v2[1] + e3 * (float)v3[1];
        A2 += e0 * (float)v0[2] + e1 * (float)v1[2] + e2 * (float)v2[2] + e3 * (float)v3[2];
        A3 += e0 * (float)v0[3] + e1 * (float)v1[3] + e2 * (float)v2[3] + e3 * (float)v3[3];
    }
    for (; j < deg; j++) {
        int s = csr_src[row + j];
        float xv = a_src[s] + ad;
        half4 v = *(const half4*)(hb + (size_t)s * 16);
        float e = __expf(fmaxf(xv, 0.2f * xv));
        sh += e;
        A0 += e * (float)v[0];
        A1 += e * (float)v[1];
        A2 += e * (float)v[2];
        A3 += e * (float)v[3];
    }
    float iv = 1.f / (sh + 1e-16f);
    float4 b = ((const float4*)bias)[sub];
    float v0 = A0 * iv + b.x;
    float v1 = A1 * iv + b.y;
    float v2 = A2 * iv + b.z;
    float v3 = A3 * iv + b.w;
    float mx = fmaxf(fmaxf(v0, v1), fmaxf(v2, v3));
    mx = fmaxf(mx, __shfl_xor(mx, 1, 64));
    mx = fmaxf(mx, __shfl_xor(mx, 2, 64));
    float se = __expf(v0 - mx) + __expf(v1 - mx) + __expf(v2 - mx) + __expf(v3 - mx);
    se += __shfl_xor(se, 1, 64);
    se += __shfl_xor(se, 2, 64);
    float ls = mx + __logf(se);
    *(float4*)&out[(size_t)node * 16 + sub * 4] =
        make_float4(v0 - ls, v1 - ls, v2 - ls, v3 - ls);
}

extern "C" void kernel_launch(void* const* d_in, const int* in_sizes, int n_in,
                              void* d_out, int out_size, void* d_ws, size_t ws_size,
                              hipStream_t stream) {
    const float* x        = (const float*)d_in[0];
    const int*   ei       = (const int*)d_in[1];
    const float* W1       = (const float*)d_in[2];
    const float* att_src1 = (const float*)d_in[3];
    const float* att_dst1 = (const float*)d_in[4];
    const float* bias1    = (const float*)d_in[5];
    const float* W2       = (const float*)d_in[6];
    const float* att_src2 = (const float*)d_in[7];
    const float* att_dst2 = (const float*)d_in[8];
    const float* bias2    = (const float*)d_in[9];
    float* out = (float*)d_out;

    const int N = in_sizes[0] / 128;
    const int E = in_sizes[1] / 2;
    const int NBK = (N + 255) >> BSH;

    char* p = (char*)d_ws;
    auto alloc = [&](size_t bytes) -> void* {
        void* r = (void*)p;
        p += (bytes + 255) & ~(size_t)255;
        return r;
    };
    __half* h1     = (__half*)alloc((size_t)N * 64 * 2);
    __half* out1   = (__half*)alloc((size_t)N * 64 * 2);
    __half* h2     = (__half*)alloc((size_t)N * 16 * 2);
    float* a_src1  = (float*)alloc((size_t)N * 4 * 4);
    float* a_dst1  = (float*)alloc((size_t)N * 4 * 4);
    float* a_src2  = (float*)alloc((size_t)N * 4);
    float* a_dst2  = (float*)alloc((size_t)N * 4);
    float* Wc      = (float*)alloc(16 * 128 * 4);
    float* Wc2     = (float*)alloc(2 * 64 * 4);
    int*   row_st  = (int*)alloc((size_t)(N + 1) * 4);
    int*   csr     = (int*)alloc((size_t)(E + N) * 4);
    int*   stage   = (int*)alloc((size_t)NBK * BCAP * 4);
    int*   cursor  = (int*)alloc((size_t)NBK * 4);
    (void)ws_size; (void)n_in; (void)out_size;

    hipMemsetAsync(cursor, 0, (size_t)NBK * 4, stream);
    k_scatter<<<(E + CHK - 1) / CHK, 256, 0, stream>>>(ei, cursor, stage, E, NBK);
    k_build<<<NBK, 256, 0, stream>>>(stage, cursor, row_st, csr,
                                     W1, att_src1, att_dst1, Wc,
                                     W2, att_src2, att_dst2, Wc2, NBK, E, N);
    k_gemm1<<<(N + 63) / 64, 256, 0, stream>>>(x, W1, Wc, h1, a_src1, a_dst1, N);
    k_agg1<<<(N + 63) / 64, 256, 0, stream>>>(row_st, csr, a_src1, a_dst1, h1, bias1, out1, N);
    k_gemm2<<<(N + 63) / 64, 256, 0, stream>>>(out1, W2, Wc2, h2, a_src2, a_dst2, N);
    k_agg2<<<(N + 63) / 64, 256, 0, stream>>>(row_st, csr, a_src2, a_dst2, h2, bias2, out, N);
}

// Round 2
// 229.418 us; speedup vs baseline: 1.0314x; 1.0314x over previous
//
#include <hip/hip_runtime.h>
#include <hip/hip_fp16.h>
#include <hip/hip_bf16.h>
#include <math.h>

// GAT 2-layer forward, MI355X. FP32 in/out, int32 edge_index.
// R15: latency-attack on agg kernels. k_agg1/k_agg2: 8 lanes/node
// (4 heads x 2 edge-parities) -> iterations halved, wave count doubled
// (grid N/32); csr indices software-pipelined one chunk ahead so next
// chunk's index loads issue before the waitcnt on current gathers.
// Parity partials combined with __shfl_xor(.,4). Byte traffic unchanged.
// scatter/build/gemm1/gemm2 unchanged from R14.

#define LRELU(v) ((v) > 0.f ? (v) : 0.2f * (v))
#define BSH 8            // 256 nodes per bucket
#define BCAP 5120        // staged capacity per bucket
#define CHK 8192         // edges per k_scatter block

typedef __attribute__((ext_vector_type(8))) short short8;
typedef __attribute__((ext_vector_type(8))) _Float16 half8;
typedef __attribute__((ext_vector_type(4))) _Float16 half4;
typedef __attribute__((ext_vector_type(4))) float float4v;

static __device__ __forceinline__ short f2bf(float f) {
    __hip_bfloat16 b = __float2bfloat16(f);
    return *reinterpret_cast<short*>(&b);
}

// Pass 1 (scan-free): histogram -> reserve per-bucket global runs -> direct
// writes into contiguous runs. No LDS reorder, no prefix scans.
__global__ __launch_bounds__(256) void k_scatter(const int* __restrict__ ei, int* __restrict__ cursor,
                                                 int* __restrict__ stage, int E, int NBK) {
    __shared__ int hist[512];
    __shared__ int cnt2[512];
    __shared__ int base[512];
    int tid = threadIdx.x;
    int e0 = blockIdx.x * CHK;
    int nedge = E - e0; if (nedge > CHK) nedge = CHK;

    for (int i = tid; i < 512; i += 256) { hist[i] = 0; cnt2[i] = 0; }
    __syncthreads();
    for (int j = tid; j < nedge; j += 256) {
        int d = ei[E + e0 + j];
        atomicAdd(&hist[d >> BSH], 1);
    }
    __syncthreads();
    for (int b = tid; b < NBK; b += 256) {
        int c = hist[b];
        if (c > 0) base[b] = b * BCAP + atomicAdd(&cursor[b], c);
    }
    __syncthreads();
    for (int j = tid; j < nedge; j += 256) {
        int s = ei[e0 + j];
        int d = ei[E + e0 + j];
        int b = d >> BSH;
        int r = atomicAdd(&cnt2[b], 1);
        stage[base[b] + r] = s | ((d & ((1 << BSH) - 1)) << 17);
    }
}

// Pass 2: per-bucket fine CSR build. Block 0 also writes row_start[N],
// Wc (gemm1 att columns) and Wc2/Wd2 (gemm2 att columns).
__global__ __launch_bounds__(256) void k_build(const int* __restrict__ stage,
                                               const int* __restrict__ cursor,
                                               int* __restrict__ row_start,
                                               int* __restrict__ csr,
                                               const float* __restrict__ W1,
                                               const float* __restrict__ att_src,
                                               const float* __restrict__ att_dst,
                                               float* __restrict__ Wc,
                                               const float* __restrict__ W2,
                                               const float* __restrict__ att_src2,
                                               const float* __restrict__ att_dst2,
                                               float* __restrict__ Wc2,
                                               int NBK, int E, int N) {
    __shared__ int cnt[256];
    __shared__ int lb[256];
    __shared__ int cur[256];
    __shared__ int sA[256];
    int b = blockIdx.x, tid = threadIdx.x;
    int nodes0 = b << BSH;
    int nnodes = N - nodes0; if (nnodes > 256) nnodes = 256;
    int partial = 0;
    for (int i = tid; i < b; i += 256) partial += cursor[i];
    sA[tid] = partial;
    __syncthreads();
    for (int off = 128; off >= 1; off >>= 1) {
        if (tid < off) sA[tid] += sA[tid + off];
        __syncthreads();
    }
    int ebase = sA[0];
    int ecnt = cursor[b];
    __syncthreads();
    if (b == 0) {
        if (tid == 0) row_start[N] = E + N;
        for (int i = tid; i < 16 * 128; i += 256) {
            int col = i >> 7, k = i & 127;
            float v = 0.f;
            if (col < 8) {
                int h = col & 3;
                const float* att = (col < 4) ? att_src : att_dst;
                #pragma unroll
                for (int c = 0; c < 16; c++) v += W1[k * 64 + h * 16 + c] * att[h * 16 + c];
            }
            Wc[i] = v;
        }
        // Wc2: col0 = W2@att_src2 (64), col1 = W2@att_dst2 (64)
        for (int i = tid; i < 128; i += 256) {
            int col = i >> 6, k = i & 63;
            const float* att = col ? att_dst2 : att_src2;
            float v = 0.f;
            #pragma unroll
            for (int c = 0; c < 16; c++) v += W2[k * 16 + c] * att[c];
            Wc2[i] = v;
        }
    }
    const int* sbk = stage + b * BCAP;
    cnt[tid] = (tid < nnodes) ? 1 : 0;  // self loop
    __syncthreads();
    for (int e = tid; e < ecnt; e += 256) {
        int l = (sbk[e] >> 17) & 255;
        atomicAdd(&cnt[l], 1);
    }
    __syncthreads();
    int myc = cnt[tid];
    sA[tid] = myc;
    __syncthreads();
    for (int off = 1; off < 256; off <<= 1) {
        int r = sA[tid] + ((tid >= off) ? sA[tid - off] : 0);
        __syncthreads();
        sA[tid] = r;
        __syncthreads();
    }
    int gb = ebase + nodes0;
    lb[tid] = sA[tid] - myc;
    cur[tid] = 1;
    __syncthreads();
    if (tid < nnodes) {
        row_start[nodes0 + tid] = gb + lb[tid];
        csr[gb + lb[tid]] = nodes0 + tid;
    }
    __syncthreads();
    for (int e = tid; e < ecnt; e += 256) {
        int v = sbk[e];
        int l = (v >> 17) & 255;
        int src = v & 0x1FFFF;
        int r = atomicAdd(&cur[l], 1);
        csr[gb + lb[l] + r] = src;
    }
}

// h1[N,64](fp16) = x[N,128] @ W1[128,64] via MFMA 16x16x32 bf16 (R9).
__global__ __launch_bounds__(256) void k_gemm1(const float* __restrict__ x,
                                               const float* __restrict__ W1,
                                               const float* __restrict__ Wc,
                                               __half* __restrict__ h1, float* __restrict__ a_src,
                                               float* __restrict__ a_dst, int N) {
    __shared__ short wt[80 * 136];   // cols 0-63: W1^T; cols 64-79: Wc
    int tid = threadIdx.x;
    for (int i = tid; i < 128 * 64; i += 256) {
        int k = i >> 6, c = i & 63;
        wt[c * 136 + k] = f2bf(W1[i]);
    }
    for (int i = tid; i < 16 * 128; i += 256) {
        int col = i >> 7, k = i & 127;
        wt[(64 + col) * 136 + k] = f2bf(Wc[i]);
    }
    __syncthreads();
    int wave = tid >> 6, lane = tid & 63;
    int m = lane & 15, q = lane >> 4;
    int nbase = blockIdx.x * 64 + wave * 16;
    int anode = nbase + m;
    bool rowok = anode < N;
    const float* xrow = x + (size_t)(rowok ? anode : 0) * 128 + q * 8;

    float4v acc[5];
    #pragma unroll
    for (int ct = 0; ct < 5; ct++)
        #pragma unroll
        for (int r = 0; r < 4; r++) acc[ct][r] = 0.f;

    #pragma unroll
    for (int kc = 0; kc < 4; kc++) {
        float4 u0 = make_float4(0.f, 0.f, 0.f, 0.f), u1 = u0;
        if (rowok) {
            u0 = *(const float4*)(xrow + kc * 32);
            u1 = *(const float4*)(xrow + kc * 32 + 4);
        }
        short8 af;
        af[0] = f2bf(u0.x); af[1] = f2bf(u0.y); af[2] = f2bf(u0.z); af[3] = f2bf(u0.w);
        af[4] = f2bf(u1.x); af[5] = f2bf(u1.y); af[6] = f2bf(u1.z); af[7] = f2bf(u1.w);
        #pragma unroll
        for (int ct = 0; ct < 5; ct++) {
            short8 bf = *(const short8*)&wt[(ct * 16 + m) * 136 + kc * 32 + q * 8];
            acc[ct] = __builtin_amdgcn_mfma_f32_16x16x32_bf16(af, bf, acc[ct], 0, 0, 0);
        }
    }
    #pragma unroll
    for (int ct = 0; ct < 4; ct++) {
        #pragma unroll
        for (int r = 0; r < 4; r++) {
            int n = nbase + q * 4 + r;
            if (n < N) h1[(size_t)n * 64 + ct * 16 + m] = __float2half(acc[ct][r]);
        }
    }
    #pragma unroll
    for (int r = 0; r < 4; r++) {
        int n = nbase + q * 4 + r;
        if (n < N) {
            float v = acc[4][r];
            if (m < 4) a_src[n * 4 + m] = v;
            else if (m < 8) a_dst[n * 4 + (m - 4)] = v;
        }
    }
}

// layer-1 aggregation (R15): 8 nodes/wave, 8 lanes/node.
// sub = lane&3 = head (owns 16 channels); par = (lane>>2)&1 = edge parity.
// Each lane walks its parity's edges: chunks of 4 edges (8/group), csr
// pipelined one chunk ahead. Parity partials combined via shfl_xor(4).
__global__ __launch_bounds__(256) void k_agg1(const int* __restrict__ row_start,
                                              const int* __restrict__ csr_src,
                                              const float* __restrict__ a_src,
                                              const float* __restrict__ a_dst,
                                              const __half* __restrict__ h1,
                                              const float* __restrict__ bias,
                                              __half* __restrict__ out1, int N) {
    int tid = threadIdx.x;
    int wave = tid >> 6, lane = tid & 63;
    int grp = lane >> 3, sub = lane & 3, par = (lane >> 2) & 1;
    int node = blockIdx.x * 32 + wave * 8 + grp;
    if (node >= N) return;
    int row = row_start[node];
    int deg = row_start[node + 1] - row;
    float adm = a_dst[node * 4 + sub];
    const _Float16* hb = (const _Float16*)h1 + sub * 16;
    const int* cp = csr_src + row + par;
    float A[16];
    #pragma unroll
    for (int c = 0; c < 16; c++) A[c] = 0.f;
    float sh = 0.f;
    int c0 = 0, c1 = 0, c2 = 0, c3 = 0;
    if (deg >= 8) { c0 = cp[0]; c1 = cp[2]; c2 = cp[4]; c3 = cp[6]; }
    int j = 0;
    for (; j + 8 <= deg; j += 8) {
        int s0 = c0, s1 = c1, s2 = c2, s3 = c3;
        // issue gathers for current chunk
        float x0 = a_src[s0 * 4 + sub] + adm;
        float x1 = a_src[s1 * 4 + sub] + adm;
        float x2 = a_src[s2 * 4 + sub] + adm;
        float x3 = a_src[s3 * 4 + sub] + adm;
        half8 p0 = *(const half8*)(hb + (size_t)s0 * 64);
        half8 q0 = *(const half8*)(hb + (size_t)s0 * 64 + 8);
        half8 p1 = *(const half8*)(hb + (size_t)s1 * 64);
        half8 q1 = *(const half8*)(hb + (size_t)s1 * 64 + 8);
        half8 p2 = *(const half8*)(hb + (size_t)s2 * 64);
        half8 q2 = *(const half8*)(hb + (size_t)s2 * 64 + 8);
        half8 p3 = *(const half8*)(hb + (size_t)s3 * 64);
        half8 q3 = *(const half8*)(hb + (size_t)s3 * 64 + 8);
        // pipeline: next chunk's csr loads issue before gather waitcnt
        if (j + 16 <= deg) {
            c0 = cp[j + 8]; c1 = cp[j + 10]; c2 = cp[j + 12]; c3 = cp[j + 14];
        }
        float e0 = __expf(fmaxf(x0, 0.2f * x0));
        float e1 = __expf(fmaxf(x1, 0.2f * x1));
        float e2 = __expf(fmaxf(x2, 0.2f * x2));
        float e3 = __expf(fmaxf(x3, 0.2f * x3));
        sh += (e0 + e1) + (e2 + e3);
        #pragma unroll
        for (int c = 0; c < 8; c++) {
            A[c]     += e0 * (float)p0[c] + e1 * (float)p1[c]
                      + e2 * (float)p2[c] + e3 * (float)p3[c];
            A[c + 8] += e0 * (float)q0[c] + e1 * (float)q1[c]
                      + e2 * (float)q2[c] + e3 * (float)q3[c];
        }
    }
    for (; j < deg; j += 2) {
        int idx = j + par;
        if (idx < deg) {
            int s = csr_src[row + idx];
            float xv = a_src[s * 4 + sub] + adm;
            half8 p = *(const half8*)(hb + (size_t)s * 64);
            half8 q = *(const half8*)(hb + (size_t)s * 64 + 8);
            float e = __expf(fmaxf(xv, 0.2f * xv));
            sh += e;
            #pragma unroll
            for (int c = 0; c < 8; c++) {
                A[c]     += e * (float)p[c];
                A[c + 8] += e * (float)q[c];
            }
        }
    }
    // combine parity halves
    sh += __shfl_xor(sh, 4, 64);
    #pragma unroll
    for (int c = 0; c < 16; c++) A[c] += __shfl_xor(A[c], 4, 64);
    if (par == 0) {
        float iv = 1.f / (sh + 1e-16f);
        const float4* bb = (const float4*)bias + sub * 4;
        union { __half2 h2v[8]; float4 f4[2]; } pk;
        #pragma unroll
        for (int c4 = 0; c4 < 4; c4++) {
            float4 b = bb[c4];
            float o0 = A[c4 * 4 + 0] * iv + b.x;
            float o1 = A[c4 * 4 + 1] * iv + b.y;
            float o2 = A[c4 * 4 + 2] * iv + b.z;
            float o3 = A[c4 * 4 + 3] * iv + b.w;
            o0 = (o0 > 0.f) ? o0 : (__expf(o0) - 1.f);
            o1 = (o1 > 0.f) ? o1 : (__expf(o1) - 1.f);
            o2 = (o2 > 0.f) ? o2 : (__expf(o2) - 1.f);
            o3 = (o3 > 0.f) ? o3 : (__expf(o3) - 1.f);
            pk.h2v[c4 * 2 + 0] = __floats2half2_rn(o0, o1);
            pk.h2v[c4 * 2 + 1] = __floats2half2_rn(o2, o3);
        }
        *(float4*)&out1[(size_t)node * 64 + sub * 16]     = pk.f4[0];
        *(float4*)&out1[(size_t)node * 64 + sub * 16 + 8] = pk.f4[1];
    }
}

// h2[N,16](fp16) = out1[N,64](fp16) @ W2[64,16] via MFMA f16; att2 dots
// via folded Wc2/Wd2 columns (2nd B-frag) — shuffle-free epilogue.
__global__ __launch_bounds__(256) void k_gemm2(const __half* __restrict__ out1,
                                               const float* __restrict__ W2,
                                               const float* __restrict__ Wc2,
                                               __half* __restrict__ h2, float* __restrict__ a_src,
                                               float* __restrict__ a_dst, int N) {
    __shared__ _Float16 wt2[16][72];   // wt2[c][k] = W2[k][c]
    __shared__ _Float16 wtb[16][72];   // col0 = Wc2, col1 = Wd2, rest 0
    int tid = threadIdx.x;
    for (int i = tid; i < 16 * 64; i += 256) {
        int k = i >> 4, c = i & 15;
        wt2[c][k] = (_Float16)W2[i];
    }
    for (int i = tid; i < 16 * 64; i += 256) {
        int col = i >> 6, k = i & 63;
        wtb[col][k] = (col < 2) ? (_Float16)Wc2[col * 64 + k] : (_Float16)0.f;
    }
    __syncthreads();
    int wave = tid >> 6, lane = tid & 63;
    int m = lane & 15, q = lane >> 4;
    int nbase = blockIdx.x * 64 + wave * 16;
    int anode = nbase + m;
    bool ok = anode < N;
    const __half* arow = out1 + (size_t)(ok ? anode : 0) * 64 + q * 8;

    float4v c1 = {0.f, 0.f, 0.f, 0.f}, c2v = {0.f, 0.f, 0.f, 0.f};
    #pragma unroll
    for (int kc = 0; kc < 2; kc++) {
        half8 af = *(const half8*)(arow + kc * 32);
        half8 b1 = *(const half8*)&wt2[m][kc * 32 + q * 8];
        half8 b2 = *(const half8*)&wtb[m][kc * 32 + q * 8];
        c1  = __builtin_amdgcn_mfma_f32_16x16x32_f16(af, b1, c1, 0, 0, 0);
        c2v = __builtin_amdgcn_mfma_f32_16x16x32_f16(af, b2, c2v, 0, 0, 0);
    }
    #pragma unroll
    for (int r = 0; r < 4; r++) {
        int n = nbase + q * 4 + r;
        if (n < N) {
            h2[(size_t)n * 16 + m] = __float2half(c1[r]);
            if (m == 0) a_src[n] = c2v[r];
            else if (m == 1) a_dst[n] = c2v[r];
        }
    }
}

// layer-2 aggregation + bias + log_softmax (R15): 8 nodes/wave,
// 8 lanes/node (4 channel-quads x 2 edge parities), csr pipelined.
__global__ __launch_bounds__(256) void k_agg2(const int* __restrict__ row_start,
                                              const int* __restrict__ csr_src,
                                              const float* __restrict__ a_src,
                                              const float* __restrict__ a_dst,
                                              const __half* __restrict__ h2,
                                              const float* __restrict__ bias,
                                              float* __restrict__ out, int N) {
    int tid = threadIdx.x;
    int wave = tid >> 6, lane = tid & 63;
    int grp = lane >> 3, sub = lane & 3, par = (lane >> 2) & 1;
    int node = blockIdx.x * 32 + wave * 8 + grp;
    if (node >= N) return;
    int row = row_start[node];
    int deg = row_start[node + 1] - row;
    float ad = a_dst[node];
    const _Float16* hb = (const _Float16*)h2 + sub * 4;
    const int* cp = csr_src + row + par;
    float A0 = 0.f, A1 = 0.f, A2 = 0.f, A3 = 0.f;
    float sh = 0.f;
    int c0 = 0, c1 = 0, c2 = 0, c3 = 0;
    if (deg >= 8) { c0 = cp[0]; c1 = cp[2]; c2 = cp[4]; c3 = cp[6]; }
    int j = 0;
    for (; j + 8 <= deg; j += 8) {
        int s0 = c0, s1 = c1, s2 = c2, s3 = c3;
        float x0 = a_src[s0] + ad;
        float x1 = a_src[s1] + ad;
        float x2 = a_src[s2] + ad;
        float x3 = a_src[s3] + ad;
        half4 v0 = *(const half4*)(hb + (size_t)s0 * 16);
        half4 v1 = *(const half4*)(hb + (size_t)s1 * 16);
        half4 v2 = *(const half4*)(hb + (size_t)s2 * 16);
        half4 v3 = *(const half4*)(hb + (size_t)s3 * 16);
        if (j + 16 <= deg) {
            c0 = cp[j + 8]; c1 = cp[j + 10]; c2 = cp[j + 12]; c3 = cp[j + 14];
        }
        float e0 = __expf(fmaxf(x0, 0.2f * x0));
        float e1 = __expf(fmaxf(x1, 0.2f * x1));
        float e2 = __expf(fmaxf(x2, 0.2f * x2));
        float e3 = __expf(fmaxf(x3, 0.2f * x3));
        sh += (e0 + e1) + (e2 + e3);
        A0 += e0 * (float)v0[0] + e1 * (float)v1[0] + e2 * (float)v2[0] + e3 * (float)v3[0];
        A1 += e0 * (float)v0[1] + e1 * (float)v1[1] + e2 * (float)v2[1] + e3 * (float)v3[1];
        A2 += e0 * (float)v0[2] + e1 * (float)v1[2] + e2 * (float)v2[2] + e3 * (float)v3[2];
        A3 += e0 * (float)v0[3] + e1 * (float)v1[3] + e2 * (float)v2[3] + e3 * (float)v3[3];
    }
    for (; j < deg; j += 2) {
        int idx = j + par;
        if (idx < deg) {
            int s = csr_src[row + idx];
            float xv = a_src[s] + ad;
            half4 v = *(const half4*)(hb + (size_t)s * 16);
            float e = __expf(fmaxf(xv, 0.2f * xv));
            sh += e;
            A0 += e * (float)v[0];
            A1 += e * (float)v[1];
            A2 += e * (float)v[2];
            A3 += e * (float)v[3];
        }
    }
    // combine parity halves
    sh += __shfl_xor(sh, 4, 64);
    A0 += __shfl_xor(A0, 4, 64);
    A1 += __shfl_xor(A1, 4, 64);
    A2 += __shfl_xor(A2, 4, 64);
    A3 += __shfl_xor(A3, 4, 64);
    float iv = 1.f / (sh + 1e-16f);
    float4 b = ((const float4*)bias)[sub];
    float v0 = A0 * iv + b.x;
    float v1 = A1 * iv + b.y;
    float v2 = A2 * iv + b.z;
    float v3 = A3 * iv + b.w;
    float mx = fmaxf(fmaxf(v0, v1), fmaxf(v2, v3));
    mx = fmaxf(mx, __shfl_xor(mx, 1, 64));
    mx = fmaxf(mx, __shfl_xor(mx, 2, 64));
    float se = __expf(v0 - mx) + __expf(v1 - mx) + __expf(v2 - mx) + __expf(v3 - mx);
    se += __shfl_xor(se, 1, 64);
    se += __shfl_xor(se, 2, 64);
    float ls = mx + __logf(se);
    if (par == 0)
        *(float4*)&out[(size_t)node * 16 + sub * 4] =
            make_float4(v0 - ls, v1 - ls, v2 - ls, v3 - ls);
}

extern "C" void kernel_launch(void* const* d_in, const int* in_sizes, int n_in,
                              void* d_out, int out_size, void* d_ws, size_t ws_size,
                              hipStream_t stream) {
    const float* x        = (const float*)d_in[0];
    const int*   ei       = (const int*)d_in[1];
    const float* W1       = (const float*)d_in[2];
    const float* att_src1 = (const float*)d_in[3];
    const float* att_dst1 = (const float*)d_in[4];
    const float* bias1    = (const float*)d_in[5];
    const float* W2       = (const float*)d_in[6];
    const float* att_src2 = (const float*)d_in[7];
    const float* att_dst2 = (const float*)d_in[8];
    const float* bias2    = (const float*)d_in[9];
    float* out = (float*)d_out;

    const int N = in_sizes[0] / 128;
    const int E = in_sizes[1] / 2;
    const int NBK = (N + 255) >> BSH;

    char* p = (char*)d_ws;
    auto alloc = [&](size_t bytes) -> void* {
        void* r = (void*)p;
        p += (bytes + 255) & ~(size_t)255;
        return r;
    };
    __half* h1     = (__half*)alloc((size_t)N * 64 * 2);
    __half* out1   = (__half*)alloc((size_t)N * 64 * 2);
    __half* h2     = (__half*)alloc((size_t)N * 16 * 2);
    float* a_src1  = (float*)alloc((size_t)N * 4 * 4);
    float* a_dst1  = (float*)alloc((size_t)N * 4 * 4);
    float* a_src2  = (float*)alloc((size_t)N * 4);
    float* a_dst2  = (float*)alloc((size_t)N * 4);
    float* Wc      = (float*)alloc(16 * 128 * 4);
    float* Wc2     = (float*)alloc(2 * 64 * 4);
    int*   row_st  = (int*)alloc((size_t)(N + 1) * 4);
    int*   csr     = (int*)alloc((size_t)(E + N) * 4);
    int*   stage   = (int*)alloc((size_t)NBK * BCAP * 4);
    int*   cursor  = (int*)alloc((size_t)NBK * 4);
    (void)ws_size; (void)n_in; (void)out_size;

    hipMemsetAsync(cursor, 0, (size_t)NBK * 4, stream);
    k_scatter<<<(E + CHK - 1) / CHK, 256, 0, stream>>>(ei, cursor, stage, E, NBK);
    k_build<<<NBK, 256, 0, stream>>>(stage, cursor, row_st, csr,
                                     W1, att_src1, att_dst1, Wc,
                                     W2, att_src2, att_dst2, Wc2, NBK, E, N);
    k_gemm1<<<(N + 63) / 64, 256, 0, stream>>>(x, W1, Wc, h1, a_src1, a_dst1, N);
    k_agg1<<<(N + 31) / 32, 256, 0, stream>>>(row_st, csr, a_src1, a_dst1, h1, bias1, out1, N);
    k_gemm2<<<(N + 63) / 64, 256, 0, stream>>>(out1, W2, Wc2, h2, a_src2, a_dst2, N);
    k_agg2<<<(N + 31) / 32, 256, 0, stream>>>(row_st, csr, a_src2, a_dst2, h2, bias2, out, N);
}